// Round 15
// baseline (305.442 us; speedup 1.0000x reference)
//
#include <hip/hip_runtime.h>
#include <hip/hip_bf16.h>

// Round 22: gemm BK=64 with attn-style XOR-chunk swizzle ([128][64] tiles,
// linear DMA dest + inverse-swizzled source + swizzled ds_read): halves
// barrier count AND removes the ~8-way LDS bank conflict of the BK=32 linear
// layout. Accumulation order unchanged (bit-identical GEMM math).
// attn (R17, 87.4 us) / prep / transpose / launch_bounds(256,3) unchanged.

#define S_LEN 2048

typedef __hip_bfloat16 bf16;
using bf16x8 = __attribute__((ext_vector_type(8))) __bf16;
using f32x4  = __attribute__((ext_vector_type(4))) float;

__device__ inline unsigned short bf16_bits(float f) {
    union { __hip_bfloat16 h; unsigned short u; } cv;
    cv.h = __float2bfloat16(f);
    return cv.u;
}

__device__ inline float bits_to_f(unsigned short u) {
    union { __hip_bfloat16 h; unsigned short u; } cv;
    cv.u = u;
    return __bfloat162float(cv.h);
}

// v_cvt_pk_bf16_f32: pack two fp32 -> two bf16 (RNE) in one instruction
__device__ inline unsigned int cvt_pk_bf16(float lo, float hi) {
    unsigned int r;
    asm volatile("v_cvt_pk_bf16_f32 %0, %1, %2" : "=v"(r) : "v"(lo), "v"(hi));
    return r;
}

// load 8 consecutive fp32, convert RNE to a bf16x8 fragment
__device__ inline bf16x8 load_cvt8(const float* __restrict__ p) {
    f32x4 a = *(const f32x4*)p;
    f32x4 b = *(const f32x4*)(p + 4);
    union { bf16x8 v; unsigned short u[8]; } r;
    r.u[0] = bf16_bits(a[0]); r.u[1] = bf16_bits(a[1]);
    r.u[2] = bf16_bits(a[2]); r.u[3] = bf16_bits(a[3]);
    r.u[4] = bf16_bits(b[0]); r.u[5] = bf16_bits(b[1]);
    r.u[6] = bf16_bits(b[2]); r.u[7] = bf16_bits(b[3]);
    return r.v;
}

// async global->LDS, 16B per lane, dest = ldsbase + lane*16 (wave-uniform base)
__device__ inline void gload_lds16(const bf16* g, bf16* l) {
    __builtin_amdgcn_global_load_lds((const __attribute__((address_space(1))) void*)g,
                                     (__attribute__((address_space(3))) void*)l,
                                     16, 0, 0);
}

// ---------------- fused prep: cvt x->bf16 + transpose wq/wk/wv --------------
// blocks [0,4096): cvt; [4096,8192): wq T; [8192,9216): wk T; [9216,10240): wv T
__global__ __launch_bounds__(256) void prep_k(const float* __restrict__ x,
                                              const float* __restrict__ wq,
                                              const float* __restrict__ wk,
                                              const float* __restrict__ wv,
                                              bf16* __restrict__ xb,
                                              bf16* __restrict__ wqT,
                                              bf16* __restrict__ wkT,
                                              bf16* __restrict__ wvT) {
    __shared__ float tile[32][33];
    int bid = blockIdx.x;
    if (bid < 4096) {
        int i = bid * 256 + threadIdx.x;    // 4096*256 = 1048576 chunks of 8
        *(bf16x8*)(xb + (size_t)i * 8) = load_cvt8(x + (size_t)i * 8);
        return;
    }
    const float* in; bf16* out; int R, C, local;
    if (bid < 8192)      { local = bid - 4096; in = wq; out = wqT; R = 2048; C = 2048; }
    else if (bid < 9216) { local = bid - 8192; in = wk; out = wkT; R = 2048; C = 512;  }
    else                 { local = bid - 9216; in = wv; out = wvT; R = 2048; C = 512;  }
    int gx = C >> 5;
    int c0 = (local % gx) * 32, r0 = (local / gx) * 32;
    int tx = threadIdx.x & 31, ty = threadIdx.x >> 5;
#pragma unroll
    for (int p = 0; p < 4; ++p)
        tile[ty + p * 8][tx] = in[(size_t)(r0 + ty + p * 8) * C + c0 + tx];
    __syncthreads();
#pragma unroll
    for (int p = 0; p < 4; ++p)
        out[(size_t)(c0 + ty + p * 8) * R + r0 + tx] = __float2bfloat16(tile[tx][ty + p * 8]);
}

// ---------------- weight transpose (wo, runs after attn) --------------------
__global__ __launch_bounds__(256) void transpose_k(const float* __restrict__ in,
                                                   bf16* __restrict__ out,
                                                   int R, int C) {
    __shared__ float tile[32][33];
    int tx = threadIdx.x & 31, ty = threadIdx.x >> 5;
    int r0 = blockIdx.y * 32, c0 = blockIdx.x * 32;
#pragma unroll
    for (int p = 0; p < 4; ++p)
        tile[ty + p * 8][tx] = in[(size_t)(r0 + ty + p * 8) * C + c0 + tx];
    __syncthreads();
#pragma unroll
    for (int p = 0; p < 4; ++p)
        out[(size_t)(c0 + ty + p * 8) * R + r0 + tx] = __float2bfloat16(tile[tx][ty + p * 8]);
}

// ---------------- GEMM: C = A[M,K] * Bt[N,K]^T (bf16 MFMA, fp32 acc)
// BK=64, [128][64] tiles, XOR-chunk swizzle (linear DMA dest, inverse-swizzled
// source, swizzled ds_read -- conflict-free). 2 barriers per 64-K step.
// XCD-bijective swizzle. launch_bounds(256,3).
// mode 2: fp32 row-major C. mode 3: fused QKV epilogue.
__global__ __launch_bounds__(256, 3) void gemm_k(const bf16* __restrict__ A,
                                                 const bf16* __restrict__ Bt,
                                                 void* __restrict__ Cv,
                                                 void* __restrict__ Cv2,
                                                 void* __restrict__ Cv3,
                                                 int M, int N, int K, int mode) {
    __shared__ bf16 As[128 * 64];   // 16 KB
    __shared__ bf16 Bs[128 * 64];   // 16 KB
    int tid  = threadIdx.x;
    int lane = tid & 63, wave = tid >> 6;
    int quad = lane >> 4, r = lane & 15;
    int wm = (wave >> 1) * 64, wn = (wave & 1) * 64;

    // XCD-aware bijective swizzle: contiguous chunk of tiles per XCD
    int nwg  = gridDim.x * gridDim.y;
    int flat = blockIdx.y * gridDim.x + blockIdx.x;
    int cpx  = nwg >> 3;
    int swz  = (flat & 7) * cpx + (flat >> 3);
    int m0 = (swz / gridDim.x) * 128, n0 = (swz % gridDim.x) * 128;

    f32x4 acc[4][4];
#pragma unroll
    for (int i = 0; i < 4; ++i)
#pragma unroll
        for (int j = 0; j < 4; ++j) acc[i][j] = (f32x4)0.0f;

    // staging geometry (attn-style): 8-row groups, 8 chunks of 8 bf16 per row
    int srow   = lane >> 3;              // 0..7 row within group
    int schunk = (lane & 7) ^ srow;      // inverse-swizzled source chunk

    for (int k0 = 0; k0 < K; k0 += 64) {
#pragma unroll
        for (int g = 0; g < 4; ++g) {
            int grp = wave * 4 + g;              // 0..15
            int row = grp * 8 + srow;
            gload_lds16(A  + (size_t)(m0 + row) * K + k0 + schunk * 8, &As[grp * 512]);
            gload_lds16(Bt + (size_t)(n0 + row) * K + k0 + schunk * 8, &Bs[grp * 512]);
        }
        __syncthreads();   // drains vmcnt(0) then barrier: tile ready
#pragma unroll
        for (int kk = 0; kk < 2; ++kk) {
            bf16x8 af[4], bfr[4];
#pragma unroll
            for (int mt = 0; mt < 4; ++mt)
                af[mt]  = *(const bf16x8*)&As[(wm + mt * 16 + r) * 64 +
                                              ((kk * 4 + quad) ^ (r & 7)) * 8];
#pragma unroll
            for (int nt = 0; nt < 4; ++nt)
                bfr[nt] = *(const bf16x8*)&Bs[(wn + nt * 16 + r) * 64 +
                                              ((kk * 4 + quad) ^ (r & 7)) * 8];
#pragma unroll
            for (int mt = 0; mt < 4; ++mt)
#pragma unroll
                for (int nt = 0; nt < 4; ++nt)
                    acc[mt][nt] = __builtin_amdgcn_mfma_f32_16x16x32_bf16(af[mt], bfr[nt],
                                                                          acc[mt][nt], 0, 0, 0);
        }
        __syncthreads();   // all reads done before next-step overwrite
    }

    if (mode == 2) {
        float* C = (float*)Cv;
#pragma unroll
        for (int mt = 0; mt < 4; ++mt)
#pragma unroll
            for (int nt = 0; nt < 4; ++nt) {
                int row = m0 + wm + mt * 16 + quad * 4;
                int col = n0 + wn + nt * 16 + r;
#pragma unroll
                for (int i = 0; i < 4; ++i)
                    C[(size_t)(row + i) * N + col] = acc[mt][nt][i];
            }
    } else {
        // mode 3: fused QKV
        if (n0 < 2048) {
            bf16* C = (bf16*)Cv;          // Q: [4096][2048]
#pragma unroll
            for (int mt = 0; mt < 4; ++mt)
#pragma unroll
                for (int nt = 0; nt < 4; ++nt) {
                    int row = m0 + wm + mt * 16 + quad * 4;
                    int col = n0 + wn + nt * 16 + r;
#pragma unroll
                    for (int i = 0; i < 4; ++i)
                        C[(size_t)(row + i) * 2048 + col] = __float2bfloat16(acc[mt][nt][i]);
                }
        } else if (n0 < 2560) {
            bf16* C = (bf16*)Cv2;         // K: [4096][512]
#pragma unroll
            for (int mt = 0; mt < 4; ++mt)
#pragma unroll
                for (int nt = 0; nt < 4; ++nt) {
                    int row = m0 + wm + mt * 16 + quad * 4;
                    int col = n0 - 2048 + wn + nt * 16 + r;
#pragma unroll
                    for (int i = 0; i < 4; ++i)
                        C[(size_t)(row + i) * 512 + col] = __float2bfloat16(acc[mt][nt][i]);
                }
        } else {
            // V transpose: Vt[b][hkv][d][s]: flat = (b*512 + col)*2048 + s
            unsigned short* C = (unsigned short*)Cv3;
#pragma unroll
            for (int mt = 0; mt < 4; ++mt)
#pragma unroll
                for (int nt = 0; nt < 4; ++nt) {
                    int rowb = m0 + wm + mt * 16 + quad * 4;
                    int col  = n0 - 2560 + wn + nt * 16 + r;
                    int b = rowb >> 11, s = rowb & 2047;
                    ushort4 pk;
                    pk.x = bf16_bits(acc[mt][nt][0]);
                    pk.y = bf16_bits(acc[mt][nt][1]);
                    pk.z = bf16_bits(acc[mt][nt][2]);
                    pk.w = bf16_bits(acc[mt][nt][3]);
                    *(ushort4*)(C + (size_t)(b * 512 + col) * 2048 + s) = pk;
                }
        }
    }
}

// ---------------- flash attention (GQA), one (b, h, 256-row q-tile) per block
// 4 q-subtiles per wave (q=64/wave): K/V LDS fragments read ONCE per iter,
// feed 4 subtiles. Static-max softmax; l via MFMA ones-fragment. K+V staged
// in LDS (dbuf DMA, XOR-chunk swizzle); swapped QK^T.
__global__ __launch_bounds__(256, 2) void attn_k(const bf16* __restrict__ Qin,
                                                 const bf16* __restrict__ Kb,
                                                 const bf16* __restrict__ Vt,
                                                 bf16* __restrict__ Aout) {
    __shared__ bf16 Ks[2][64 * 64];   // 16384 B, XOR-swizzled 16B chunks
    __shared__ bf16 Vs[2][64 * 64];   // 16384 B, same swizzle
    __shared__ bf16 Pl[4][16 * 64];   //  8192 B, wave-private, XOR-swizzled

    int tid = threadIdx.x, lane = tid & 63, w = tid >> 6;
    int quad = lane >> 4, r = lane & 15;
    int qt = blockIdx.x, h = blockIdx.y, b = blockIdx.z;
    int hk = h >> 2;

    // Q fragments for 4 subtiles, pre-scaled by 1/8 (exact in bf16)
    bf16x8 qf[4][2];
#pragma unroll
    for (int s = 0; s < 4; ++s) {
        int q0 = qt * 256 + s * 64 + w * 16;
#pragma unroll
        for (int f = 0; f < 2; ++f) {
            bf16x8 v = *(const bf16x8*)(Qin + (size_t)(b * S_LEN + q0 + r) * 2048 + h * 64 + f * 32 + quad * 8);
            union { bf16x8 v; unsigned short u[8]; } i_, o_;
            i_.v = v;
#pragma unroll
            for (int j = 0; j < 8; ++j) o_.u[j] = bf16_bits(bits_to_f(i_.u[j]) * 0.125f);
            qf[s][f] = o_.v;
        }
    }

    // ones fragment for the l-MFMA
    bf16x8 onesf;
    {
        union { bf16x8 v; unsigned short u[8]; } o_;
#pragma unroll
        for (int j = 0; j < 8; ++j) o_.u[j] = 0x3F80;   // bf16(1.0)
        onesf = o_.v;
    }

    const bf16* Kbase = Kb + (size_t)b * S_LEN * 512 + hk * 64;
    const bf16* Vbase = Vt + (size_t)(b * 512 + hk * 64) * 2048;
    char* myP = (char*)&Pl[w][0];

    // staging geometry: each wave stages 16 K-rows and 16 V-rows (2+2 DMA/tile)
    int srow   = lane >> 3;              // 0..7 row within 8-row group
    int schunk = (lane & 7) ^ srow;      // inverse-swizzled source chunk
    int wrow0 = w * 16, wrow1 = w * 16 + 8;

    f32x4 oacc[4][4];
#pragma unroll
    for (int s = 0; s < 4; ++s)
#pragma unroll
        for (int dt = 0; dt < 4; ++dt) oacc[s][dt] = (f32x4)0.0f;
    f32x4 lacc[4];
#pragma unroll
    for (int s = 0; s < 4; ++s) lacc[s] = (f32x4)0.0f;

    // prologue: stage tile 0 into buf 0
    gload_lds16(Kbase + (size_t)(wrow0 + srow) * 512 + schunk * 8, &Ks[0][wrow0 * 64]);
    gload_lds16(Kbase + (size_t)(wrow1 + srow) * 512 + schunk * 8, &Ks[0][wrow1 * 64]);
    gload_lds16(Vbase + (size_t)(wrow0 + srow) * 2048 + 0 + schunk * 8, &Vs[0][wrow0 * 64]);
    gload_lds16(Vbase + (size_t)(wrow1 + srow) * 2048 + 0 + schunk * 8, &Vs[0][wrow1 * 64]);
    __syncthreads();

#define ATTN_STEP(BUF, K0)                                                               \
    do {                                                                                 \
        int k0n_ = (K0) + 64;                                                            \
        if (k0n_ < S_LEN) {                                                              \
            gload_lds16(Kbase + (size_t)(k0n_ + wrow0 + srow) * 512 + schunk * 8,        \
                        &Ks[(BUF) ^ 1][wrow0 * 64]);                                     \
            gload_lds16(Kbase + (size_t)(k0n_ + wrow1 + srow) * 512 + schunk * 8,        \
                        &Ks[(BUF) ^ 1][wrow1 * 64]);                                     \
            gload_lds16(Vbase + (size_t)(wrow0 + srow) * 2048 + k0n_ + schunk * 8,       \
                        &Vs[(BUF) ^ 1][wrow0 * 64]);                                     \
            gload_lds16(Vbase + (size_t)(wrow1 + srow) * 2048 + k0n_ + schunk * 8,       \
                        &Vs[(BUF) ^ 1][wrow1 * 64]);                                     \
        }                                                                                \
        f32x4 S[4][4];                                                                   \
        {                                                                                \
            bf16x8 kf[4][2];                                                             \
            _Pragma("unroll")                                                            \
            for (int t = 0; t < 4; ++t)                                                  \
                _Pragma("unroll")                                                        \
                for (int half = 0; half < 2; ++half)                                     \
                    kf[t][half] = *(const bf16x8*)&Ks[BUF][(t * 16 + r) * 64 +           \
                                                    ((half * 4 + quad) ^ (r & 7)) * 8];  \
            __builtin_amdgcn_s_setprio(1);                                               \
            _Pragma("unroll")                                                            \
            for (int s = 0; s < 4; ++s)                                                  \
                _Pragma("unroll")                                                        \
                for (int t = 0; t < 4; ++t) {                                            \
                    f32x4 z = (f32x4)0.0f;                                               \
                    z = __builtin_amdgcn_mfma_f32_16x16x32_bf16(kf[t][0], qf[s][0], z, 0, 0, 0); \
                    z = __builtin_amdgcn_mfma_f32_16x16x32_bf16(kf[t][1], qf[s][1], z, 0, 0, 0); \
                    S[s][t] = z;                                                         \
                }                                                                        \
            __builtin_amdgcn_s_setprio(0);                                               \
        }                                                                                \
        bf16x8 vf[4][2];                                                                 \
        _Pragma("unroll")                                                                \
        for (int dt = 0; dt < 4; ++dt)                                                   \
            _Pragma("unroll")                                                            \
            for (int half = 0; half < 2; ++half)                                         \
                vf[dt][half] = *(const bf16x8*)&Vs[BUF][(dt * 16 + r) * 64 +             \
                                                ((half * 4 + quad) ^ (r & 7)) * 8];      \
        _Pragma("unroll")                                                                \
        for (int s = 0; s < 4; ++s) {                                                    \
            float p[16];                                                                 \
            _Pragma("unroll")                                                            \
            for (int t = 0; t < 4; ++t)                                                  \
                _Pragma("unroll")                                                        \
                for (int i = 0; i < 4; ++i) p[t * 4 + i] = __expf(S[s][t][i]);           \
            _Pragma("unroll")                                                            \
            for (int t = 0; t < 4; ++t) {                                                \
                uint2 pk;                                                                \
                pk.x = cvt_pk_bf16(p[t * 4 + 0], p[t * 4 + 1]);                          \
                pk.y = cvt_pk_bf16(p[t * 4 + 2], p[t * 4 + 3]);                          \
                *(uint2*)(myP + r * 128 + (((t * 2 + (quad >> 1)) ^ (r & 7)) * 16) +     \
                          (quad & 1) * 8) = pk;                                          \
            }                                                                            \
            bf16x8 pf0 = *(const bf16x8*)(myP + r * 128 + ((quad ^ (r & 7)) * 16));      \
            bf16x8 pf1 = *(const bf16x8*)(myP + r * 128 + (((4 + quad) ^ (r & 7)) * 16));\
            __builtin_amdgcn_s_setprio(1);                                               \
            lacc[s] = __builtin_amdgcn_mfma_f32_16x16x32_bf16(pf0, onesf, lacc[s], 0, 0, 0); \
            lacc[s] = __builtin_amdgcn_mfma_f32_16x16x32_bf16(pf1, onesf, lacc[s], 0, 0, 0); \
            _Pragma("unroll")                                                            \
            for (int dt = 0; dt < 4; ++dt) {                                             \
                f32x4 o = oacc[s][dt];                                                   \
                o = __builtin_amdgcn_mfma_f32_16x16x32_bf16(pf0, vf[dt][0], o, 0, 0, 0); \
                o = __builtin_amdgcn_mfma_f32_16x16x32_bf16(pf1, vf[dt][1], o, 0, 0, 0); \
                oacc[s][dt] = o;                                                         \
            }                                                                            \
            __builtin_amdgcn_s_setprio(0);                                               \
        }                                                                                \
        __syncthreads();                                                                 \
    } while (0)

    for (int itp = 0; itp < S_LEN / 128; ++itp) {
        int base = itp * 128;
        ATTN_STEP(0, base);
        ATTN_STEP(1, base + 64);
    }
#undef ATTN_STEP

#pragma unroll
    for (int s = 0; s < 4; ++s) {
        int q0 = qt * 256 + s * 64 + w * 16;
        float linv[4];
#pragma unroll
        for (int i = 0; i < 4; ++i) linv[i] = 1.0f / lacc[s][i];
#pragma unroll
        for (int dt = 0; dt < 4; ++dt)
#pragma unroll
            for (int i = 0; i < 4; ++i)
                Aout[(size_t)(b * S_LEN + q0 + quad * 4 + i) * 2048 + h * 64 + dt * 16 + r] =
                    __float2bfloat16(oacc[s][dt][i] * linv[i]);
    }
}

extern "C" void kernel_launch(void* const* d_in, const int* in_sizes, int n_in,
                              void* d_out, int out_size, void* d_ws, size_t ws_size,
                              hipStream_t stream) {
    const float* x  = (const float*)d_in[0];
    const float* wq = (const float*)d_in[1];
    const float* wk = (const float*)d_in[2];
    const float* wv = (const float*)d_in[3];
    const float* wo = (const float*)d_in[4];
    char* ws = (char*)d_ws;

    // d_out 32MB: [0,16M)=Qb(bf16), [16,32M)=xb(bf16) -- both dead before the
    // final fp32 GEMM overwrites d_out.
    // ws 24MB phased:
    //   phase 1: [0,12M) wqkvT ([3072][2048] bf16: wq^T | wk^T | wv^T)
    //   phase 2: [0,16M) attnOut, [16,20M) Kb, [20,24M) Vt
    //   phase 3: [0,16M) attnOut, [16,24M) woT
    bf16* wqT  = (bf16*)(ws + 0);
    bf16* wkT  = (bf16*)(ws + 8388608);
    bf16* wvT  = (bf16*)(ws + 10485760);
    bf16* attn = (bf16*)(ws + 0);
    bf16* Kb   = (bf16*)(ws + 16777216);
    bf16* Vtb  = (bf16*)(ws + 20971520);
    bf16* woT  = (bf16*)(ws + 16777216);
    bf16* Qb   = (bf16*)d_out;
    bf16* xb   = (bf16*)((char*)d_out + 16777216);

    // fused prep: cvt x + transpose wq/wk/wv (one dispatch)
    prep_k<<<dim3(10240), 256, 0, stream>>>(x, wq, wk, wv, xb, wqT, wkT, wvT);

    // fused QKV projection: 768 blocks, per-region epilogue
    gemm_k<<<dim3(24, 32), 256, 0, stream>>>(xb, wqT, Qb, Kb, Vtb, 4096, 3072, 2048, 3);

    attn_k<<<dim3(8, 32, 2), 256, 0, stream>>>(Qb, Kb, Vtb, attn);

    // Kb/Vt dead; put woT in their slot
    transpose_k<<<dim3(64, 64), 256, 0, stream>>>(wo, woT, 2048, 2048);

    // fp32 epilogue into d_out (Qb/xb dead)
    gemm_k<<<dim3(16, 32), 256, 0, stream>>>(attn, woT, d_out, nullptr, nullptr, 4096, 2048, 2048, 2);
}

// Round 16
// 304.071 us; speedup vs baseline: 1.0045x; 1.0045x over previous
//
#include <hip/hip_runtime.h>
#include <hip/hip_bf16.h>

// Round 23: gemm reverted to R21's BK=32 body (R22's BK=64 swizzle fixed a
// non-existent conflict: 64B row-stride = 2-way aliasing = free) with
// launch_bounds bumped (256,3)->(256,4): hot loop needs ~116 VGPR, so 128-cap
// should fit and give a 4th wave/SIMD to cover barrier drains.
// attn (R17, 87.5 us) / prep / transpose unchanged.

#define S_LEN 2048

typedef __hip_bfloat16 bf16;
using bf16x8 = __attribute__((ext_vector_type(8))) __bf16;
using f32x4  = __attribute__((ext_vector_type(4))) float;

__device__ inline unsigned short bf16_bits(float f) {
    union { __hip_bfloat16 h; unsigned short u; } cv;
    cv.h = __float2bfloat16(f);
    return cv.u;
}

__device__ inline float bits_to_f(unsigned short u) {
    union { __hip_bfloat16 h; unsigned short u; } cv;
    cv.u = u;
    return __bfloat162float(cv.h);
}

// v_cvt_pk_bf16_f32: pack two fp32 -> two bf16 (RNE) in one instruction
__device__ inline unsigned int cvt_pk_bf16(float lo, float hi) {
    unsigned int r;
    asm volatile("v_cvt_pk_bf16_f32 %0, %1, %2" : "=v"(r) : "v"(lo), "v"(hi));
    return r;
}

// load 8 consecutive fp32, convert RNE to a bf16x8 fragment
__device__ inline bf16x8 load_cvt8(const float* __restrict__ p) {
    f32x4 a = *(const f32x4*)p;
    f32x4 b = *(const f32x4*)(p + 4);
    union { bf16x8 v; unsigned short u[8]; } r;
    r.u[0] = bf16_bits(a[0]); r.u[1] = bf16_bits(a[1]);
    r.u[2] = bf16_bits(a[2]); r.u[3] = bf16_bits(a[3]);
    r.u[4] = bf16_bits(b[0]); r.u[5] = bf16_bits(b[1]);
    r.u[6] = bf16_bits(b[2]); r.u[7] = bf16_bits(b[3]);
    return r.v;
}

// async global->LDS, 16B per lane, dest = ldsbase + lane*16 (wave-uniform base)
__device__ inline void gload_lds16(const bf16* g, bf16* l) {
    __builtin_amdgcn_global_load_lds((const __attribute__((address_space(1))) void*)g,
                                     (__attribute__((address_space(3))) void*)l,
                                     16, 0, 0);
}

// ---------------- fused prep: cvt x->bf16 + transpose wq/wk/wv --------------
// blocks [0,4096): cvt; [4096,8192): wq T; [8192,9216): wk T; [9216,10240): wv T
__global__ __launch_bounds__(256) void prep_k(const float* __restrict__ x,
                                              const float* __restrict__ wq,
                                              const float* __restrict__ wk,
                                              const float* __restrict__ wv,
                                              bf16* __restrict__ xb,
                                              bf16* __restrict__ wqT,
                                              bf16* __restrict__ wkT,
                                              bf16* __restrict__ wvT) {
    __shared__ float tile[32][33];
    int bid = blockIdx.x;
    if (bid < 4096) {
        int i = bid * 256 + threadIdx.x;    // 4096*256 = 1048576 chunks of 8
        *(bf16x8*)(xb + (size_t)i * 8) = load_cvt8(x + (size_t)i * 8);
        return;
    }
    const float* in; bf16* out; int R, C, local;
    if (bid < 8192)      { local = bid - 4096; in = wq; out = wqT; R = 2048; C = 2048; }
    else if (bid < 9216) { local = bid - 8192; in = wk; out = wkT; R = 2048; C = 512;  }
    else                 { local = bid - 9216; in = wv; out = wvT; R = 2048; C = 512;  }
    int gx = C >> 5;
    int c0 = (local % gx) * 32, r0 = (local / gx) * 32;
    int tx = threadIdx.x & 31, ty = threadIdx.x >> 5;
#pragma unroll
    for (int p = 0; p < 4; ++p)
        tile[ty + p * 8][tx] = in[(size_t)(r0 + ty + p * 8) * C + c0 + tx];
    __syncthreads();
#pragma unroll
    for (int p = 0; p < 4; ++p)
        out[(size_t)(c0 + ty + p * 8) * R + r0 + tx] = __float2bfloat16(tile[tx][ty + p * 8]);
}

// ---------------- weight transpose (wo, runs after attn) --------------------
__global__ __launch_bounds__(256) void transpose_k(const float* __restrict__ in,
                                                   bf16* __restrict__ out,
                                                   int R, int C) {
    __shared__ float tile[32][33];
    int tx = threadIdx.x & 31, ty = threadIdx.x >> 5;
    int r0 = blockIdx.y * 32, c0 = blockIdx.x * 32;
#pragma unroll
    for (int p = 0; p < 4; ++p)
        tile[ty + p * 8][tx] = in[(size_t)(r0 + ty + p * 8) * C + c0 + tx];
    __syncthreads();
#pragma unroll
    for (int p = 0; p < 4; ++p)
        out[(size_t)(c0 + ty + p * 8) * R + r0 + tx] = __float2bfloat16(tile[tx][ty + p * 8]);
}

// ---------------- GEMM: C = A[M,K] * Bt[N,K]^T (bf16 MFMA, fp32 acc)
// m97 structure (2-barrier, single 16KB LDS buffers) + XCD-bijective swizzle.
// launch_bounds(256,4): cap VGPR 128 -> 4 waves/SIMD (hot loop needs ~116).
// mode 2: fp32 row-major C. mode 3: fused QKV epilogue.
__global__ __launch_bounds__(256, 4) void gemm_k(const bf16* __restrict__ A,
                                                 const bf16* __restrict__ Bt,
                                                 void* __restrict__ Cv,
                                                 void* __restrict__ Cv2,
                                                 void* __restrict__ Cv3,
                                                 int M, int N, int K, int mode) {
    __shared__ bf16 As[128 * 32];
    __shared__ bf16 Bs[128 * 32];
    int tid  = threadIdx.x;
    int lane = tid & 63, wave = tid >> 6;
    int quad = lane >> 4, r = lane & 15;
    int wm = (wave >> 1) * 64, wn = (wave & 1) * 64;

    // XCD-aware bijective swizzle: contiguous chunk of tiles per XCD
    int nwg  = gridDim.x * gridDim.y;
    int flat = blockIdx.y * gridDim.x + blockIdx.x;
    int cpx  = nwg >> 3;
    int swz  = (flat & 7) * cpx + (flat >> 3);
    int m0 = (swz / gridDim.x) * 128, n0 = (swz % gridDim.x) * 128;

    f32x4 acc[4][4];
#pragma unroll
    for (int i = 0; i < 4; ++i)
#pragma unroll
        for (int j = 0; j < 4; ++j) acc[i][j] = (f32x4)0.0f;

    int rg = lane >> 2;          // 0..15 row within 16-row group
    int ck = (lane & 3) << 3;    // 8-elem (16B) chunk within 32-col row

    for (int k0 = 0; k0 < K; k0 += 32) {
#pragma unroll
        for (int g = 0; g < 2; ++g) {
            int grp = wave * 2 + g;              // 0..7
            int row = grp * 16 + rg;
            gload_lds16(A  + (size_t)(m0 + row) * K + k0 + ck, &As[grp * 512]);
            gload_lds16(Bt + (size_t)(n0 + row) * K + k0 + ck, &Bs[grp * 512]);
        }
        __syncthreads();   // drains vmcnt(0) then barrier: tile ready
        bf16x8 af[4], bfr[4];
#pragma unroll
        for (int mt = 0; mt < 4; ++mt) af[mt]  = *(const bf16x8*)&As[(wm + mt * 16 + r) * 32 + quad * 8];
#pragma unroll
        for (int nt = 0; nt < 4; ++nt) bfr[nt] = *(const bf16x8*)&Bs[(wn + nt * 16 + r) * 32 + quad * 8];
#pragma unroll
        for (int mt = 0; mt < 4; ++mt)
#pragma unroll
            for (int nt = 0; nt < 4; ++nt)
                acc[mt][nt] = __builtin_amdgcn_mfma_f32_16x16x32_bf16(af[mt], bfr[nt], acc[mt][nt], 0, 0, 0);
        __syncthreads();   // all reads done before next-step overwrite
    }

    if (mode == 2) {
        float* C = (float*)Cv;
#pragma unroll
        for (int mt = 0; mt < 4; ++mt)
#pragma unroll
            for (int nt = 0; nt < 4; ++nt) {
                int row = m0 + wm + mt * 16 + quad * 4;
                int col = n0 + wn + nt * 16 + r;
#pragma unroll
                for (int i = 0; i < 4; ++i)
                    C[(size_t)(row + i) * N + col] = acc[mt][nt][i];
            }
    } else {
        // mode 3: fused QKV
        if (n0 < 2048) {
            bf16* C = (bf16*)Cv;          // Q: [4096][2048]
#pragma unroll
            for (int mt = 0; mt < 4; ++mt)
#pragma unroll
                for (int nt = 0; nt < 4; ++nt) {
                    int row = m0 + wm + mt * 16 + quad * 4;
                    int col = n0 + wn + nt * 16 + r;
#pragma unroll
                    for (int i = 0; i < 4; ++i)
                        C[(size_t)(row + i) * 2048 + col] = __float2bfloat16(acc[mt][nt][i]);
                }
        } else if (n0 < 2560) {
            bf16* C = (bf16*)Cv2;         // K: [4096][512]
#pragma unroll
            for (int mt = 0; mt < 4; ++mt)
#pragma unroll
                for (int nt = 0; nt < 4; ++nt) {
                    int row = m0 + wm + mt * 16 + quad * 4;
                    int col = n0 - 2048 + wn + nt * 16 + r;
#pragma unroll
                    for (int i = 0; i < 4; ++i)
                        C[(size_t)(row + i) * 512 + col] = __float2bfloat16(acc[mt][nt][i]);
                }
        } else {
            // V transpose: Vt[b][hkv][d][s]: flat = (b*512 + col)*2048 + s
            unsigned short* C = (unsigned short*)Cv3;
#pragma unroll
            for (int mt = 0; mt < 4; ++mt)
#pragma unroll
                for (int nt = 0; nt < 4; ++nt) {
                    int rowb = m0 + wm + mt * 16 + quad * 4;
                    int col  = n0 - 2560 + wn + nt * 16 + r;
                    int b = rowb >> 11, s = rowb & 2047;
                    ushort4 pk;
                    pk.x = bf16_bits(acc[mt][nt][0]);
                    pk.y = bf16_bits(acc[mt][nt][1]);
                    pk.z = bf16_bits(acc[mt][nt][2]);
                    pk.w = bf16_bits(acc[mt][nt][3]);
                    *(ushort4*)(C + (size_t)(b * 512 + col) * 2048 + s) = pk;
                }
        }
    }
}

// ---------------- flash attention (GQA), one (b, h, 256-row q-tile) per block
// 4 q-subtiles per wave (q=64/wave): K/V LDS fragments read ONCE per iter,
// feed 4 subtiles. Static-max softmax; l via MFMA ones-fragment. K+V staged
// in LDS (dbuf DMA, XOR-chunk swizzle); swapped QK^T.
__global__ __launch_bounds__(256, 2) void attn_k(const bf16* __restrict__ Qin,
                                                 const bf16* __restrict__ Kb,
                                                 const bf16* __restrict__ Vt,
                                                 bf16* __restrict__ Aout) {
    __shared__ bf16 Ks[2][64 * 64];   // 16384 B, XOR-swizzled 16B chunks
    __shared__ bf16 Vs[2][64 * 64];   // 16384 B, same swizzle
    __shared__ bf16 Pl[4][16 * 64];   //  8192 B, wave-private, XOR-swizzled

    int tid = threadIdx.x, lane = tid & 63, w = tid >> 6;
    int quad = lane >> 4, r = lane & 15;
    int qt = blockIdx.x, h = blockIdx.y, b = blockIdx.z;
    int hk = h >> 2;

    // Q fragments for 4 subtiles, pre-scaled by 1/8 (exact in bf16)
    bf16x8 qf[4][2];
#pragma unroll
    for (int s = 0; s < 4; ++s) {
        int q0 = qt * 256 + s * 64 + w * 16;
#pragma unroll
        for (int f = 0; f < 2; ++f) {
            bf16x8 v = *(const bf16x8*)(Qin + (size_t)(b * S_LEN + q0 + r) * 2048 + h * 64 + f * 32 + quad * 8);
            union { bf16x8 v; unsigned short u[8]; } i_, o_;
            i_.v = v;
#pragma unroll
            for (int j = 0; j < 8; ++j) o_.u[j] = bf16_bits(bits_to_f(i_.u[j]) * 0.125f);
            qf[s][f] = o_.v;
        }
    }

    // ones fragment for the l-MFMA
    bf16x8 onesf;
    {
        union { bf16x8 v; unsigned short u[8]; } o_;
#pragma unroll
        for (int j = 0; j < 8; ++j) o_.u[j] = 0x3F80;   // bf16(1.0)
        onesf = o_.v;
    }

    const bf16* Kbase = Kb + (size_t)b * S_LEN * 512 + hk * 64;
    const bf16* Vbase = Vt + (size_t)(b * 512 + hk * 64) * 2048;
    char* myP = (char*)&Pl[w][0];

    // staging geometry: each wave stages 16 K-rows and 16 V-rows (2+2 DMA/tile)
    int srow   = lane >> 3;              // 0..7 row within 8-row group
    int schunk = (lane & 7) ^ srow;      // inverse-swizzled source chunk
    int wrow0 = w * 16, wrow1 = w * 16 + 8;

    f32x4 oacc[4][4];
#pragma unroll
    for (int s = 0; s < 4; ++s)
#pragma unroll
        for (int dt = 0; dt < 4; ++dt) oacc[s][dt] = (f32x4)0.0f;
    f32x4 lacc[4];
#pragma unroll
    for (int s = 0; s < 4; ++s) lacc[s] = (f32x4)0.0f;

    // prologue: stage tile 0 into buf 0
    gload_lds16(Kbase + (size_t)(wrow0 + srow) * 512 + schunk * 8, &Ks[0][wrow0 * 64]);
    gload_lds16(Kbase + (size_t)(wrow1 + srow) * 512 + schunk * 8, &Ks[0][wrow1 * 64]);
    gload_lds16(Vbase + (size_t)(wrow0 + srow) * 2048 + 0 + schunk * 8, &Vs[0][wrow0 * 64]);
    gload_lds16(Vbase + (size_t)(wrow1 + srow) * 2048 + 0 + schunk * 8, &Vs[0][wrow1 * 64]);
    __syncthreads();

#define ATTN_STEP(BUF, K0)                                                               \
    do {                                                                                 \
        int k0n_ = (K0) + 64;                                                            \
        if (k0n_ < S_LEN) {                                                              \
            gload_lds16(Kbase + (size_t)(k0n_ + wrow0 + srow) * 512 + schunk * 8,        \
                        &Ks[(BUF) ^ 1][wrow0 * 64]);                                     \
            gload_lds16(Kbase + (size_t)(k0n_ + wrow1 + srow) * 512 + schunk * 8,        \
                        &Ks[(BUF) ^ 1][wrow1 * 64]);                                     \
            gload_lds16(Vbase + (size_t)(wrow0 + srow) * 2048 + k0n_ + schunk * 8,       \
                        &Vs[(BUF) ^ 1][wrow0 * 64]);                                     \
            gload_lds16(Vbase + (size_t)(wrow1 + srow) * 2048 + k0n_ + schunk * 8,       \
                        &Vs[(BUF) ^ 1][wrow1 * 64]);                                     \
        }                                                                                \
        f32x4 S[4][4];                                                                   \
        {                                                                                \
            bf16x8 kf[4][2];                                                             \
            _Pragma("unroll")                                                            \
            for (int t = 0; t < 4; ++t)                                                  \
                _Pragma("unroll")                                                        \
                for (int half = 0; half < 2; ++half)                                     \
                    kf[t][half] = *(const bf16x8*)&Ks[BUF][(t * 16 + r) * 64 +           \
                                                    ((half * 4 + quad) ^ (r & 7)) * 8];  \
            __builtin_amdgcn_s_setprio(1);                                               \
            _Pragma("unroll")                                                            \
            for (int s = 0; s < 4; ++s)                                                  \
                _Pragma("unroll")                                                        \
                for (int t = 0; t < 4; ++t) {                                            \
                    f32x4 z = (f32x4)0.0f;                                               \
                    z = __builtin_amdgcn_mfma_f32_16x16x32_bf16(kf[t][0], qf[s][0], z, 0, 0, 0); \
                    z = __builtin_amdgcn_mfma_f32_16x16x32_bf16(kf[t][1], qf[s][1], z, 0, 0, 0); \
                    S[s][t] = z;                                                         \
                }                                                                        \
            __builtin_amdgcn_s_setprio(0);                                               \
        }                                                                                \
        bf16x8 vf[4][2];                                                                 \
        _Pragma("unroll")                                                                \
        for (int dt = 0; dt < 4; ++dt)                                                   \
            _Pragma("unroll")                                                            \
            for (int half = 0; half < 2; ++half)                                         \
                vf[dt][half] = *(const bf16x8*)&Vs[BUF][(dt * 16 + r) * 64 +             \
                                                ((half * 4 + quad) ^ (r & 7)) * 8];      \
        _Pragma("unroll")                                                                \
        for (int s = 0; s < 4; ++s) {                                                    \
            float p[16];                                                                 \
            _Pragma("unroll")                                                            \
            for (int t = 0; t < 4; ++t)                                                  \
                _Pragma("unroll")                                                        \
                for (int i = 0; i < 4; ++i) p[t * 4 + i] = __expf(S[s][t][i]);           \
            _Pragma("unroll")                                                            \
            for (int t = 0; t < 4; ++t) {                                                \
                uint2 pk;                                                                \
                pk.x = cvt_pk_bf16(p[t * 4 + 0], p[t * 4 + 1]);                          \
                pk.y = cvt_pk_bf16(p[t * 4 + 2], p[t * 4 + 3]);                          \
                *(uint2*)(myP + r * 128 + (((t * 2 + (quad >> 1)) ^ (r & 7)) * 16) +     \
                          (quad & 1) * 8) = pk;                                          \
            }                                                                            \
            bf16x8 pf0 = *(const bf16x8*)(myP + r * 128 + ((quad ^ (r & 7)) * 16));      \
            bf16x8 pf1 = *(const bf16x8*)(myP + r * 128 + (((4 + quad) ^ (r & 7)) * 16));\
            __builtin_amdgcn_s_setprio(1);                                               \
            lacc[s] = __builtin_amdgcn_mfma_f32_16x16x32_bf16(pf0, onesf, lacc[s], 0, 0, 0); \
            lacc[s] = __builtin_amdgcn_mfma_f32_16x16x32_bf16(pf1, onesf, lacc[s], 0, 0, 0); \
            _Pragma("unroll")                                                            \
            for (int dt = 0; dt < 4; ++dt) {                                             \
                f32x4 o = oacc[s][dt];                                                   \
                o = __builtin_amdgcn_mfma_f32_16x16x32_bf16(pf0, vf[dt][0], o, 0, 0, 0); \
                o = __builtin_amdgcn_mfma_f32_16x16x32_bf16(pf1, vf[dt][1], o, 0, 0, 0); \
                oacc[s][dt] = o;                                                         \
            }                                                                            \
            __builtin_amdgcn_s_setprio(0);                                               \
        }                                                                                \
        __syncthreads();                                                                 \
    } while (0)

    for (int itp = 0; itp < S_LEN / 128; ++itp) {
        int base = itp * 128;
        ATTN_STEP(0, base);
        ATTN_STEP(1, base + 64);
    }
#undef ATTN_STEP

#pragma unroll
    for (int s = 0; s < 4; ++s) {
        int q0 = qt * 256 + s * 64 + w * 16;
        float linv[4];
#pragma unroll
        for (int i = 0; i < 4; ++i) linv[i] = 1.0f / lacc[s][i];
#pragma unroll
        for (int dt = 0; dt < 4; ++dt)
#pragma unroll
            for (int i = 0; i < 4; ++i)
                Aout[(size_t)(b * S_LEN + q0 + quad * 4 + i) * 2048 + h * 64 + dt * 16 + r] =
                    __float2bfloat16(oacc[s][dt][i] * linv[i]);
    }
}

extern "C" void kernel_launch(void* const* d_in, const int* in_sizes, int n_in,
                              void* d_out, int out_size, void* d_ws, size_t ws_size,
                              hipStream_t stream) {
    const float* x  = (const float*)d_in[0];
    const float* wq = (const float*)d_in[1];
    const float* wk = (const float*)d_in[2];
    const float* wv = (const float*)d_in[3];
    const float* wo = (const float*)d_in[4];
    char* ws = (char*)d_ws;

    // d_out 32MB: [0,16M)=Qb(bf16), [16,32M)=xb(bf16) -- both dead before the
    // final fp32 GEMM overwrites d_out.
    // ws 24MB phased:
    //   phase 1: [0,12M) wqkvT ([3072][2048] bf16: wq^T | wk^T | wv^T)
    //   phase 2: [0,16M) attnOut, [16,20M) Kb, [20,24M) Vt
    //   phase 3: [0,16M) attnOut, [16,24M) woT
    bf16* wqT  = (bf16*)(ws + 0);
    bf16* wkT  = (bf16*)(ws + 8388608);
    bf16* wvT  = (bf16*)(ws + 10485760);
    bf16* attn = (bf16*)(ws + 0);
    bf16* Kb   = (bf16*)(ws + 16777216);
    bf16* Vtb  = (bf16*)(ws + 20971520);
    bf16* woT  = (bf16*)(ws + 16777216);
    bf16* Qb   = (bf16*)d_out;
    bf16* xb   = (bf16*)((char*)d_out + 16777216);

    // fused prep: cvt x + transpose wq/wk/wv (one dispatch)
    prep_k<<<dim3(10240), 256, 0, stream>>>(x, wq, wk, wv, xb, wqT, wkT, wvT);

    // fused QKV projection: 768 blocks, per-region epilogue
    gemm_k<<<dim3(24, 32), 256, 0, stream>>>(xb, wqT, Qb, Kb, Vtb, 4096, 3072, 2048, 3);

    attn_k<<<dim3(8, 32, 2), 256, 0, stream>>>(Qb, Kb, Vtb, attn);

    // Kb/Vt dead; put woT in their slot
    transpose_k<<<dim3(64, 64), 256, 0, stream>>>(wo, woT, 2048, 2048);

    // fp32 epilogue into d_out (Qb/xb dead)
    gemm_k<<<dim3(16, 32), 256, 0, stream>>>(attn, woT, d_out, nullptr, nullptr, 4096, 2048, 2048, 2);
}

// Round 17
// 298.894 us; speedup vs baseline: 1.0219x; 1.0173x over previous
//
#include <hip/hip_runtime.h>
#include <hip/hip_bf16.h>

// Round 24: exact restore of R21, the best measured configuration (299.7 us).
// R22 (BK=64 swizzle) and R23 (launch_bounds(256,4)) both regressed; R23 also
// showed co-compilation codegen perturbation (attn slowed 87.5->98 with
// identical source). gemm: m97 BK=32 + XCD swizzle + launch_bounds(256,3).
// attn: R17 structure (4 q-subtiles/wave, static-max softmax, LDS-DMA K/V).

#define S_LEN 2048

typedef __hip_bfloat16 bf16;
using bf16x8 = __attribute__((ext_vector_type(8))) __bf16;
using f32x4  = __attribute__((ext_vector_type(4))) float;

__device__ inline unsigned short bf16_bits(float f) {
    union { __hip_bfloat16 h; unsigned short u; } cv;
    cv.h = __float2bfloat16(f);
    return cv.u;
}

__device__ inline float bits_to_f(unsigned short u) {
    union { __hip_bfloat16 h; unsigned short u; } cv;
    cv.u = u;
    return __bfloat162float(cv.h);
}

// v_cvt_pk_bf16_f32: pack two fp32 -> two bf16 (RNE) in one instruction
__device__ inline unsigned int cvt_pk_bf16(float lo, float hi) {
    unsigned int r;
    asm volatile("v_cvt_pk_bf16_f32 %0, %1, %2" : "=v"(r) : "v"(lo), "v"(hi));
    return r;
}

// load 8 consecutive fp32, convert RNE to a bf16x8 fragment
__device__ inline bf16x8 load_cvt8(const float* __restrict__ p) {
    f32x4 a = *(const f32x4*)p;
    f32x4 b = *(const f32x4*)(p + 4);
    union { bf16x8 v; unsigned short u[8]; } r;
    r.u[0] = bf16_bits(a[0]); r.u[1] = bf16_bits(a[1]);
    r.u[2] = bf16_bits(a[2]); r.u[3] = bf16_bits(a[3]);
    r.u[4] = bf16_bits(b[0]); r.u[5] = bf16_bits(b[1]);
    r.u[6] = bf16_bits(b[2]); r.u[7] = bf16_bits(b[3]);
    return r.v;
}

// async global->LDS, 16B per lane, dest = ldsbase + lane*16 (wave-uniform base)
__device__ inline void gload_lds16(const bf16* g, bf16* l) {
    __builtin_amdgcn_global_load_lds((const __attribute__((address_space(1))) void*)g,
                                     (__attribute__((address_space(3))) void*)l,
                                     16, 0, 0);
}

// ---------------- fused prep: cvt x->bf16 + transpose wq/wk/wv --------------
// blocks [0,4096): cvt; [4096,8192): wq T; [8192,9216): wk T; [9216,10240): wv T
__global__ __launch_bounds__(256) void prep_k(const float* __restrict__ x,
                                              const float* __restrict__ wq,
                                              const float* __restrict__ wk,
                                              const float* __restrict__ wv,
                                              bf16* __restrict__ xb,
                                              bf16* __restrict__ wqT,
                                              bf16* __restrict__ wkT,
                                              bf16* __restrict__ wvT) {
    __shared__ float tile[32][33];
    int bid = blockIdx.x;
    if (bid < 4096) {
        int i = bid * 256 + threadIdx.x;    // 4096*256 = 1048576 chunks of 8
        *(bf16x8*)(xb + (size_t)i * 8) = load_cvt8(x + (size_t)i * 8);
        return;
    }
    const float* in; bf16* out; int R, C, local;
    if (bid < 8192)      { local = bid - 4096; in = wq; out = wqT; R = 2048; C = 2048; }
    else if (bid < 9216) { local = bid - 8192; in = wk; out = wkT; R = 2048; C = 512;  }
    else                 { local = bid - 9216; in = wv; out = wvT; R = 2048; C = 512;  }
    int gx = C >> 5;
    int c0 = (local % gx) * 32, r0 = (local / gx) * 32;
    int tx = threadIdx.x & 31, ty = threadIdx.x >> 5;
#pragma unroll
    for (int p = 0; p < 4; ++p)
        tile[ty + p * 8][tx] = in[(size_t)(r0 + ty + p * 8) * C + c0 + tx];
    __syncthreads();
#pragma unroll
    for (int p = 0; p < 4; ++p)
        out[(size_t)(c0 + ty + p * 8) * R + r0 + tx] = __float2bfloat16(tile[tx][ty + p * 8]);
}

// ---------------- weight transpose (wo, runs after attn) --------------------
__global__ __launch_bounds__(256) void transpose_k(const float* __restrict__ in,
                                                   bf16* __restrict__ out,
                                                   int R, int C) {
    __shared__ float tile[32][33];
    int tx = threadIdx.x & 31, ty = threadIdx.x >> 5;
    int r0 = blockIdx.y * 32, c0 = blockIdx.x * 32;
#pragma unroll
    for (int p = 0; p < 4; ++p)
        tile[ty + p * 8][tx] = in[(size_t)(r0 + ty + p * 8) * C + c0 + tx];
    __syncthreads();
#pragma unroll
    for (int p = 0; p < 4; ++p)
        out[(size_t)(c0 + ty + p * 8) * R + r0 + tx] = __float2bfloat16(tile[tx][ty + p * 8]);
}

// ---------------- GEMM: C = A[M,K] * Bt[N,K]^T (bf16 MFMA, fp32 acc)
// m97 structure (2-barrier, single 16KB LDS buffers) + XCD-bijective swizzle.
// launch_bounds(256,3): cap VGPR ~168 so 3 blocks/CU are guaranteed.
// mode 2: fp32 row-major C. mode 3: fused QKV epilogue.
__global__ __launch_bounds__(256, 3) void gemm_k(const bf16* __restrict__ A,
                                                 const bf16* __restrict__ Bt,
                                                 void* __restrict__ Cv,
                                                 void* __restrict__ Cv2,
                                                 void* __restrict__ Cv3,
                                                 int M, int N, int K, int mode) {
    __shared__ bf16 As[128 * 32];
    __shared__ bf16 Bs[128 * 32];
    int tid  = threadIdx.x;
    int lane = tid & 63, wave = tid >> 6;
    int quad = lane >> 4, r = lane & 15;
    int wm = (wave >> 1) * 64, wn = (wave & 1) * 64;

    // XCD-aware bijective swizzle: contiguous chunk of tiles per XCD
    int nwg  = gridDim.x * gridDim.y;
    int flat = blockIdx.y * gridDim.x + blockIdx.x;
    int cpx  = nwg >> 3;
    int swz  = (flat & 7) * cpx + (flat >> 3);
    int m0 = (swz / gridDim.x) * 128, n0 = (swz % gridDim.x) * 128;

    f32x4 acc[4][4];
#pragma unroll
    for (int i = 0; i < 4; ++i)
#pragma unroll
        for (int j = 0; j < 4; ++j) acc[i][j] = (f32x4)0.0f;

    int rg = lane >> 2;          // 0..15 row within 16-row group
    int ck = (lane & 3) << 3;    // 8-elem (16B) chunk within 32-col row

    for (int k0 = 0; k0 < K; k0 += 32) {
#pragma unroll
        for (int g = 0; g < 2; ++g) {
            int grp = wave * 2 + g;              // 0..7
            int row = grp * 16 + rg;
            gload_lds16(A  + (size_t)(m0 + row) * K + k0 + ck, &As[grp * 512]);
            gload_lds16(Bt + (size_t)(n0 + row) * K + k0 + ck, &Bs[grp * 512]);
        }
        __syncthreads();   // drains vmcnt(0) then barrier: tile ready
        bf16x8 af[4], bfr[4];
#pragma unroll
        for (int mt = 0; mt < 4; ++mt) af[mt]  = *(const bf16x8*)&As[(wm + mt * 16 + r) * 32 + quad * 8];
#pragma unroll
        for (int nt = 0; nt < 4; ++nt) bfr[nt] = *(const bf16x8*)&Bs[(wn + nt * 16 + r) * 32 + quad * 8];
#pragma unroll
        for (int mt = 0; mt < 4; ++mt)
#pragma unroll
            for (int nt = 0; nt < 4; ++nt)
                acc[mt][nt] = __builtin_amdgcn_mfma_f32_16x16x32_bf16(af[mt], bfr[nt], acc[mt][nt], 0, 0, 0);
        __syncthreads();   // all reads done before next-step overwrite
    }

    if (mode == 2) {
        float* C = (float*)Cv;
#pragma unroll
        for (int mt = 0; mt < 4; ++mt)
#pragma unroll
            for (int nt = 0; nt < 4; ++nt) {
                int row = m0 + wm + mt * 16 + quad * 4;
                int col = n0 + wn + nt * 16 + r;
#pragma unroll
                for (int i = 0; i < 4; ++i)
                    C[(size_t)(row + i) * N + col] = acc[mt][nt][i];
            }
    } else {
        // mode 3: fused QKV
        if (n0 < 2048) {
            bf16* C = (bf16*)Cv;          // Q: [4096][2048]
#pragma unroll
            for (int mt = 0; mt < 4; ++mt)
#pragma unroll
                for (int nt = 0; nt < 4; ++nt) {
                    int row = m0 + wm + mt * 16 + quad * 4;
                    int col = n0 + wn + nt * 16 + r;
#pragma unroll
                    for (int i = 0; i < 4; ++i)
                        C[(size_t)(row + i) * 2048 + col] = __float2bfloat16(acc[mt][nt][i]);
                }
        } else if (n0 < 2560) {
            bf16* C = (bf16*)Cv2;         // K: [4096][512]
#pragma unroll
            for (int mt = 0; mt < 4; ++mt)
#pragma unroll
                for (int nt = 0; nt < 4; ++nt) {
                    int row = m0 + wm + mt * 16 + quad * 4;
                    int col = n0 - 2048 + wn + nt * 16 + r;
#pragma unroll
                    for (int i = 0; i < 4; ++i)
                        C[(size_t)(row + i) * 512 + col] = __float2bfloat16(acc[mt][nt][i]);
                }
        } else {
            // V transpose: Vt[b][hkv][d][s]: flat = (b*512 + col)*2048 + s
            unsigned short* C = (unsigned short*)Cv3;
#pragma unroll
            for (int mt = 0; mt < 4; ++mt)
#pragma unroll
                for (int nt = 0; nt < 4; ++nt) {
                    int rowb = m0 + wm + mt * 16 + quad * 4;
                    int col  = n0 - 2560 + wn + nt * 16 + r;
                    int b = rowb >> 11, s = rowb & 2047;
                    ushort4 pk;
                    pk.x = bf16_bits(acc[mt][nt][0]);
                    pk.y = bf16_bits(acc[mt][nt][1]);
                    pk.z = bf16_bits(acc[mt][nt][2]);
                    pk.w = bf16_bits(acc[mt][nt][3]);
                    *(ushort4*)(C + (size_t)(b * 512 + col) * 2048 + s) = pk;
                }
        }
    }
}

// ---------------- flash attention (GQA), one (b, h, 256-row q-tile) per block
// 4 q-subtiles per wave (q=64/wave): K/V LDS fragments read ONCE per iter,
// feed 4 subtiles. Static-max softmax; l via MFMA ones-fragment. K+V staged
// in LDS (dbuf DMA, XOR-chunk swizzle); swapped QK^T.
__global__ __launch_bounds__(256, 2) void attn_k(const bf16* __restrict__ Qin,
                                                 const bf16* __restrict__ Kb,
                                                 const bf16* __restrict__ Vt,
                                                 bf16* __restrict__ Aout) {
    __shared__ bf16 Ks[2][64 * 64];   // 16384 B, XOR-swizzled 16B chunks
    __shared__ bf16 Vs[2][64 * 64];   // 16384 B, same swizzle
    __shared__ bf16 Pl[4][16 * 64];   //  8192 B, wave-private, XOR-swizzled

    int tid = threadIdx.x, lane = tid & 63, w = tid >> 6;
    int quad = lane >> 4, r = lane & 15;
    int qt = blockIdx.x, h = blockIdx.y, b = blockIdx.z;
    int hk = h >> 2;

    // Q fragments for 4 subtiles, pre-scaled by 1/8 (exact in bf16)
    bf16x8 qf[4][2];
#pragma unroll
    for (int s = 0; s < 4; ++s) {
        int q0 = qt * 256 + s * 64 + w * 16;
#pragma unroll
        for (int f = 0; f < 2; ++f) {
            bf16x8 v = *(const bf16x8*)(Qin + (size_t)(b * S_LEN + q0 + r) * 2048 + h * 64 + f * 32 + quad * 8);
            union { bf16x8 v; unsigned short u[8]; } i_, o_;
            i_.v = v;
#pragma unroll
            for (int j = 0; j < 8; ++j) o_.u[j] = bf16_bits(bits_to_f(i_.u[j]) * 0.125f);
            qf[s][f] = o_.v;
        }
    }

    // ones fragment for the l-MFMA
    bf16x8 onesf;
    {
        union { bf16x8 v; unsigned short u[8]; } o_;
#pragma unroll
        for (int j = 0; j < 8; ++j) o_.u[j] = 0x3F80;   // bf16(1.0)
        onesf = o_.v;
    }

    const bf16* Kbase = Kb + (size_t)b * S_LEN * 512 + hk * 64;
    const bf16* Vbase = Vt + (size_t)(b * 512 + hk * 64) * 2048;
    char* myP = (char*)&Pl[w][0];

    // staging geometry: each wave stages 16 K-rows and 16 V-rows (2+2 DMA/tile)
    int srow   = lane >> 3;              // 0..7 row within 8-row group
    int schunk = (lane & 7) ^ srow;      // inverse-swizzled source chunk
    int wrow0 = w * 16, wrow1 = w * 16 + 8;

    f32x4 oacc[4][4];
#pragma unroll
    for (int s = 0; s < 4; ++s)
#pragma unroll
        for (int dt = 0; dt < 4; ++dt) oacc[s][dt] = (f32x4)0.0f;
    f32x4 lacc[4];
#pragma unroll
    for (int s = 0; s < 4; ++s) lacc[s] = (f32x4)0.0f;

    // prologue: stage tile 0 into buf 0
    gload_lds16(Kbase + (size_t)(wrow0 + srow) * 512 + schunk * 8, &Ks[0][wrow0 * 64]);
    gload_lds16(Kbase + (size_t)(wrow1 + srow) * 512 + schunk * 8, &Ks[0][wrow1 * 64]);
    gload_lds16(Vbase + (size_t)(wrow0 + srow) * 2048 + 0 + schunk * 8, &Vs[0][wrow0 * 64]);
    gload_lds16(Vbase + (size_t)(wrow1 + srow) * 2048 + 0 + schunk * 8, &Vs[0][wrow1 * 64]);
    __syncthreads();

#define ATTN_STEP(BUF, K0)                                                               \
    do {                                                                                 \
        int k0n_ = (K0) + 64;                                                            \
        if (k0n_ < S_LEN) {                                                              \
            gload_lds16(Kbase + (size_t)(k0n_ + wrow0 + srow) * 512 + schunk * 8,        \
                        &Ks[(BUF) ^ 1][wrow0 * 64]);                                     \
            gload_lds16(Kbase + (size_t)(k0n_ + wrow1 + srow) * 512 + schunk * 8,        \
                        &Ks[(BUF) ^ 1][wrow1 * 64]);                                     \
            gload_lds16(Vbase + (size_t)(wrow0 + srow) * 2048 + k0n_ + schunk * 8,       \
                        &Vs[(BUF) ^ 1][wrow0 * 64]);                                     \
            gload_lds16(Vbase + (size_t)(wrow1 + srow) * 2048 + k0n_ + schunk * 8,       \
                        &Vs[(BUF) ^ 1][wrow1 * 64]);                                     \
        }                                                                                \
        f32x4 S[4][4];                                                                   \
        {                                                                                \
            bf16x8 kf[4][2];                                                             \
            _Pragma("unroll")                                                            \
            for (int t = 0; t < 4; ++t)                                                  \
                _Pragma("unroll")                                                        \
                for (int half = 0; half < 2; ++half)                                     \
                    kf[t][half] = *(const bf16x8*)&Ks[BUF][(t * 16 + r) * 64 +           \
                                                    ((half * 4 + quad) ^ (r & 7)) * 8];  \
            __builtin_amdgcn_s_setprio(1);                                               \
            _Pragma("unroll")                                                            \
            for (int s = 0; s < 4; ++s)                                                  \
                _Pragma("unroll")                                                        \
                for (int t = 0; t < 4; ++t) {                                            \
                    f32x4 z = (f32x4)0.0f;                                               \
                    z = __builtin_amdgcn_mfma_f32_16x16x32_bf16(kf[t][0], qf[s][0], z, 0, 0, 0); \
                    z = __builtin_amdgcn_mfma_f32_16x16x32_bf16(kf[t][1], qf[s][1], z, 0, 0, 0); \
                    S[s][t] = z;                                                         \
                }                                                                        \
            __builtin_amdgcn_s_setprio(0);                                               \
        }                                                                                \
        bf16x8 vf[4][2];                                                                 \
        _Pragma("unroll")                                                                \
        for (int dt = 0; dt < 4; ++dt)                                                   \
            _Pragma("unroll")                                                            \
            for (int half = 0; half < 2; ++half)                                         \
                vf[dt][half] = *(const bf16x8*)&Vs[BUF][(dt * 16 + r) * 64 +             \
                                                ((half * 4 + quad) ^ (r & 7)) * 8];      \
        _Pragma("unroll")                                                                \
        for (int s = 0; s < 4; ++s) {                                                    \
            float p[16];                                                                 \
            _Pragma("unroll")                                                            \
            for (int t = 0; t < 4; ++t)                                                  \
                _Pragma("unroll")                                                        \
                for (int i = 0; i < 4; ++i) p[t * 4 + i] = __expf(S[s][t][i]);           \
            _Pragma("unroll")                                                            \
            for (int t = 0; t < 4; ++t) {                                                \
                uint2 pk;                                                                \
                pk.x = cvt_pk_bf16(p[t * 4 + 0], p[t * 4 + 1]);                          \
                pk.y = cvt_pk_bf16(p[t * 4 + 2], p[t * 4 + 3]);                          \
                *(uint2*)(myP + r * 128 + (((t * 2 + (quad >> 1)) ^ (r & 7)) * 16) +     \
                          (quad & 1) * 8) = pk;                                          \
            }                                                                            \
            bf16x8 pf0 = *(const bf16x8*)(myP + r * 128 + ((quad ^ (r & 7)) * 16));      \
            bf16x8 pf1 = *(const bf16x8*)(myP + r * 128 + (((4 + quad) ^ (r & 7)) * 16));\
            __builtin_amdgcn_s_setprio(1);                                               \
            lacc[s] = __builtin_amdgcn_mfma_f32_16x16x32_bf16(pf0, onesf, lacc[s], 0, 0, 0); \
            lacc[s] = __builtin_amdgcn_mfma_f32_16x16x32_bf16(pf1, onesf, lacc[s], 0, 0, 0); \
            _Pragma("unroll")                                                            \
            for (int dt = 0; dt < 4; ++dt) {                                             \
                f32x4 o = oacc[s][dt];                                                   \
                o = __builtin_amdgcn_mfma_f32_16x16x32_bf16(pf0, vf[dt][0], o, 0, 0, 0); \
                o = __builtin_amdgcn_mfma_f32_16x16x32_bf16(pf1, vf[dt][1], o, 0, 0, 0); \
                oacc[s][dt] = o;                                                         \
            }                                                                            \
            __builtin_amdgcn_s_setprio(0);                                               \
        }                                                                                \
        __syncthreads();                                                                 \
    } while (0)

    for (int itp = 0; itp < S_LEN / 128; ++itp) {
        int base = itp * 128;
        ATTN_STEP(0, base);
        ATTN_STEP(1, base + 64);
    }
#undef ATTN_STEP

#pragma unroll
    for (int s = 0; s < 4; ++s) {
        int q0 = qt * 256 + s * 64 + w * 16;
        float linv[4];
#pragma unroll
        for (int i = 0; i < 4; ++i) linv[i] = 1.0f / lacc[s][i];
#pragma unroll
        for (int dt = 0; dt < 4; ++dt)
#pragma unroll
            for (int i = 0; i < 4; ++i)
                Aout[(size_t)(b * S_LEN + q0 + quad * 4 + i) * 2048 + h * 64 + dt * 16 + r] =
                    __float2bfloat16(oacc[s][dt][i] * linv[i]);
    }
}

extern "C" void kernel_launch(void* const* d_in, const int* in_sizes, int n_in,
                              void* d_out, int out_size, void* d_ws, size_t ws_size,
                              hipStream_t stream) {
    const float* x  = (const float*)d_in[0];
    const float* wq = (const float*)d_in[1];
    const float* wk = (const float*)d_in[2];
    const float* wv = (const float*)d_in[3];
    const float* wo = (const float*)d_in[4];
    char* ws = (char*)d_ws;

    // d_out 32MB: [0,16M)=Qb(bf16), [16,32M)=xb(bf16) -- both dead before the
    // final fp32 GEMM overwrites d_out.
    // ws 24MB phased:
    //   phase 1: [0,12M) wqkvT ([3072][2048] bf16: wq^T | wk^T | wv^T)
    //   phase 2: [0,16M) attnOut, [16,20M) Kb, [20,24M) Vt
    //   phase 3: [0,16M) attnOut, [16,24M) woT
    bf16* wqT  = (bf16*)(ws + 0);
    bf16* wkT  = (bf16*)(ws + 8388608);
    bf16* wvT  = (bf16*)(ws + 10485760);
    bf16* attn = (bf16*)(ws + 0);
    bf16* Kb   = (bf16*)(ws + 16777216);
    bf16* Vtb  = (bf16*)(ws + 20971520);
    bf16* woT  = (bf16*)(ws + 16777216);
    bf16* Qb   = (bf16*)d_out;
    bf16* xb   = (bf16*)((char*)d_out + 16777216);

    // fused prep: cvt x + transpose wq/wk/wv (one dispatch)
    prep_k<<<dim3(10240), 256, 0, stream>>>(x, wq, wk, wv, xb, wqT, wkT, wvT);

    // fused QKV projection: 768 blocks, per-region epilogue
    gemm_k<<<dim3(24, 32), 256, 0, stream>>>(xb, wqT, Qb, Kb, Vtb, 4096, 3072, 2048, 3);

    attn_k<<<dim3(8, 32, 2), 256, 0, stream>>>(Qb, Kb, Vtb, attn);

    // Kb/Vt dead; put woT in their slot
    transpose_k<<<dim3(64, 64), 256, 0, stream>>>(wo, woT, 2048, 2048);

    // fp32 epilogue into d_out (Qb/xb dead)
    gemm_k<<<dim3(16, 32), 256, 0, stream>>>(attn, woT, d_out, nullptr, nullptr, 4096, 2048, 2048, 2);
}